// Round 13
// baseline (304.281 us; speedup 1.0000x reference)
//
#include <hip/hip_runtime.h>
#include <math.h>

#define B 256
#define C 1000
#define D 128
#define QN 262144

// output layout (floats):
// [0]        output        B*C      = 256000
// [256000]   output2       B*C      = 256000
// [512000]   features      (2B+Q)*D = 33619968
// [34131968] pseudo_labels (2B+Q)   = 262656
// [34394624] score_prot    B*C      = 256000
// [34650624] protos        C*D      = 128000
#define OFF_FEAT   512000
#define OFF_LBL    34131968
#define OFF_SCORE  34394624
#define OFF_PROTO  34650624

#define N_Q4   (QN * D / 4)          /* 8388608 float4: queue -> features[2B:] */
#define N_O4   (B * C / 4)           /* 64000 */
#define N_F4   (B * D / 4)           /* 8192  */
#define N_P4   (QN / 4)              /* 65536 */

#define DST_Q4   ((OFF_FEAT + 2 * B * D) / 4)
#define DST_O24  (B * C / 4)
#define DST_QF4  (OFF_FEAT / 4)
#define DST_KF4  (OFF_FEAT / 4 + N_F4)
#define DST_P4   ((OFF_LBL + 2 * B) / 4)

// small-segment ranges (float4 indices)
#define SM_O2  (N_O4)                         /* after: output2 */
#define SM_Q   (2 * N_O4)                     /* after: q       */
#define SM_K   (2 * N_O4 + N_F4)              /* after: k       */
#define SM_P   (2 * N_O4 + 2 * N_F4)          /* after: pseudo  */
#define SM_TOT (2 * N_O4 + 2 * N_F4 + N_P4)   /* 209920 float4  */

// queue copy split: K1 takes a leading one-shot slice; K3 grid-strides the rest
#define Q_TILES   (N_Q4 / 1024)               /* 8192 tiles of 1024 float4      */
#define K1_TILES  640
#define POOL_BASE4 ((size_t)K1_TILES * 1024)  /* 655360  */
#define POOL_N4    ((size_t)(Q_TILES - K1_TILES) * 1024)   /* 7733248 */

// K1 role boundaries: argmax | scoreprot | small | copy tiles
#define R1_SP     256                         /* [256,512): scoreprot           */
#define R1_SM     512                         /* [512,1332): small segments     */
#define SM_BLKS   ((SM_TOT + 255) / 256)      /* 820 */
#define R1_CP     (R1_SM + SM_BLKS)           /* 1332: copy tiles start         */
#define K1_GRID   (R1_CP + K1_TILES)          /* 1972 */

// K3: lean m13-style copy
#define K3_GRID   4096

// ---------------- K1: argmax + scoreprot + small segments + copy slice ---------
// Shared memory hand-aliased into one block so every path (incl. copy tiles)
// carries the same modest 5.5 KB: scoreprot needs C+256+128=1384 floats (max).
__global__ __launch_bounds__(256) void k1_kernel(
    const float* __restrict__ q,
    const float* __restrict__ kk,
    const float* __restrict__ output,
    const float* __restrict__ output2,
    const float* __restrict__ partial_Y,
    const float* __restrict__ prototypes,
    const float4* __restrict__ queue,
    const float* __restrict__ queue_pseudo,
    int* __restrict__ labels,          // d_ws: [0,256) labels
    float* __restrict__ out)
{
    const int bid = blockIdx.x;
    const int tid = threadIdx.x;
    __shared__ float smem[1384];

    if (bid < B) {
        // ---- argmax of output*partial_Y per row (first-occurrence ties) -------
        float* sv = smem;                  // 256 floats
        int*   si = (int*)(smem + 256);    // 256 ints
        const float* row = output + (size_t)bid * C;
        const float* msk = partial_Y + (size_t)bid * C;

        float best = -INFINITY;
        int bidx = C;
        for (int c = tid; c < C; c += 256) {
            float v = row[c] * msk[c];
            if (v > best) { best = v; bidx = c; }
        }
        sv[tid] = best; si[tid] = bidx;
        __syncthreads();
        for (int s = 128; s > 0; s >>= 1) {
            if (tid < s) {
                float v2 = sv[tid + s]; int i2 = si[tid + s];
                if (v2 > sv[tid] || (v2 == sv[tid] && i2 < si[tid])) {
                    sv[tid] = v2; si[tid] = i2;
                }
            }
            __syncthreads();
        }
        if (tid == 0) {
            int lab = si[0];
            labels[bid] = lab;
            float f = (float)lab;
            out[OFF_LBL + bid]     = f;
            out[OFF_LBL + B + bid] = f;
        }
        return;
    }

    if (bid < R1_SM) {
        // ---- score_prot = softmax(q @ P^T), one row per block (orig protos) ---
        const int b = bid - R1_SP;
        float* logits = smem;              // C floats
        float* red    = smem + C;          // 256 floats
        float* qs     = smem + C + 256;    // 128 floats
        if (tid < D) qs[tid] = q[(size_t)b * D + tid];
        __syncthreads();

        for (int c = tid; c < C; c += 256) {
            const float4* p4 = (const float4*)(prototypes + (size_t)c * D);
            const float4* q4 = (const float4*)qs;
            float acc = 0.f;
            #pragma unroll
            for (int d = 0; d < D / 4; ++d) {
                float4 pv = p4[d];
                float4 qv = q4[d];
                acc += pv.x * qv.x + pv.y * qv.y + pv.z * qv.z + pv.w * qv.w;
            }
            logits[c] = acc;
        }
        __syncthreads();

        float lm = -INFINITY;
        for (int c = tid; c < C; c += 256) lm = fmaxf(lm, logits[c]);
        red[tid] = lm;
        __syncthreads();
        for (int s = 128; s > 0; s >>= 1) {
            if (tid < s) red[tid] = fmaxf(red[tid], red[tid + s]);
            __syncthreads();
        }
        const float m = red[0];
        __syncthreads();

        float psum = 0.f;
        for (int c = tid; c < C; c += 256) {
            float e = expf(logits[c] - m);
            logits[c] = e;
            psum += e;
        }
        red[tid] = psum;
        __syncthreads();
        for (int s = 128; s > 0; s >>= 1) {
            if (tid < s) red[tid] += red[tid + s];
            __syncthreads();
        }
        const float denom = red[0];

        for (int c = tid; c < C; c += 256)
            out[OFF_SCORE + (size_t)b * C + c] = logits[c] / denom;
        return;
    }

    if (bid < R1_CP) {
        // ---- small segments: output, output2, q->feat, k->feat, pseudo --------
        const size_t i = (size_t)(bid - R1_SM) * 256 + tid;
        float4* __restrict__ out4 = (float4*)out;
        if (i < SM_O2)       out4[i]                     = ((const float4*)output)[i];
        else if (i < SM_Q)   out4[DST_O24 + (i - SM_O2)] = ((const float4*)output2)[i - SM_O2];
        else if (i < SM_K)   out4[DST_QF4 + (i - SM_Q)]  = ((const float4*)q)[i - SM_Q];
        else if (i < SM_P)   out4[DST_KF4 + (i - SM_K)]  = ((const float4*)kk)[i - SM_K];
        else if (i < SM_TOT) out4[DST_P4 + (i - SM_P)]   = ((const float4*)queue_pseudo)[i - SM_P];
        return;
    }

    // ---- one-shot queue copy tile: keep HBM busy while roles run -------------
    const size_t base = (size_t)(bid - R1_CP) * 1024 + tid;
    float4* __restrict__ dst = (float4*)out + DST_Q4;
    float4 a = queue[base];
    float4 b = queue[base + 256];
    float4 c = queue[base + 512];
    float4 d = queue[base + 768];
    dst[base]       = a;
    dst[base + 256] = b;
    dst[base + 512] = c;
    dst[base + 768] = d;
}

// ---------------- K2: EMA scatter + L2 normalize (needs all labels) ------------
__global__ __launch_bounds__(256) void ema_kernel(
    const float* __restrict__ q,
    const float* __restrict__ prototypes,
    const int* __restrict__ labels,
    float* __restrict__ out)
{
    const int ebid = blockIdx.x;         // 0..249, 4 classes/block (2 at a time)
    const int tid  = threadIdx.x;
    const int half = tid >> 7;
    const int d    = tid & 127;

    __shared__ int   lab[B];
    __shared__ float ss[256];
    for (int i = tid; i < B; i += 256) lab[i] = labels[i];
    __syncthreads();

    #pragma unroll
    for (int kcl = 0; kcl < 2; ++kcl) {
        const int c = 4 * ebid + 2 * kcl + half;
        float val = prototypes[(size_t)c * D + d];
        #pragma unroll 8
        for (int b = 0; b < B; ++b) {
            if (lab[b] == c) {
                val = val * 0.99f + 0.01f * q[(size_t)b * D + d];
            }
        }
        ss[tid] = val * val;
        __syncthreads();
        for (int s = 64; s > 0; s >>= 1) {
            if (d < s) ss[tid] += ss[tid + s];
            __syncthreads();
        }
        float r = fmaxf(sqrtf(ss[half * 128]), 1e-12f);
        out[OFF_PROTO + (size_t)c * D + d] = val / r;
        __syncthreads();
    }
}

// ---------------- K3: lean m13-replica copy — no LDS, minimal VGPR -------------
// Single-stream grid-stride dst[i]=src[i]; the pattern measured at 6.29 TB/s.
__global__ __launch_bounds__(256) void copy_kernel(
    const float4* __restrict__ src, float4* __restrict__ dst)
{
    const size_t stride = (size_t)gridDim.x * blockDim.x;
    for (size_t i = (size_t)blockIdx.x * blockDim.x + threadIdx.x;
         i < POOL_N4; i += stride)
        dst[i] = src[i];
}

extern "C" void kernel_launch(void* const* d_in, const int* in_sizes, int n_in,
                              void* d_out, int out_size, void* d_ws, size_t ws_size,
                              hipStream_t stream) {
    const float* q            = (const float*)d_in[0];
    const float* k            = (const float*)d_in[1];
    const float* output       = (const float*)d_in[2];
    const float* output2      = (const float*)d_in[3];
    const float* partial_Y    = (const float*)d_in[4];
    const float* prototypes   = (const float*)d_in[5];
    const float* queue        = (const float*)d_in[6];
    const float* queue_pseudo = (const float*)d_in[7];

    float* out  = (float*)d_out;
    int* labels = (int*)d_ws;

    // K1: argmax + scoreprot + small segments, overlapped with a copy slice
    k1_kernel<<<K1_GRID, 256, 0, stream>>>(
        q, k, output, output2, partial_Y, prototypes,
        (const float4*)queue, queue_pseudo, labels, out);

    // K2: EMA (stream-ordered after K1's argmax)
    ema_kernel<<<C / 4, 256, 0, stream>>>(q, prototypes, labels, out);

    // K3: pure lean copy of the remaining queue -> features
    copy_kernel<<<K3_GRID, 256, 0, stream>>>(
        (const float4*)queue + POOL_BASE4,
        (float4*)out + DST_Q4 + POOL_BASE4);
}

// Round 18
// 275.680 us; speedup vs baseline: 1.1037x; 1.1037x over previous
//
#include <hip/hip_runtime.h>
#include <math.h>

#define B 256
#define C 1000
#define D 128
#define QN 262144

// output layout (floats):
// [0]        output        B*C      = 256000
// [256000]   output2       B*C      = 256000
// [512000]   features      (2B+Q)*D = 33619968
// [34131968] pseudo_labels (2B+Q)   = 262656
// [34394624] score_prot    B*C      = 256000
// [34650624] protos        C*D      = 128000
#define OFF_FEAT   512000
#define OFF_LBL    34131968
#define OFF_SCORE  34394624
#define OFF_PROTO  34650624

#define N_Q4   (QN * D / 4)          /* 8388608 float4: queue -> features[2B:] */
#define N_O4   (B * C / 4)           /* 64000 */
#define N_F4   (B * D / 4)           /* 8192  */
#define N_P4   (QN / 4)              /* 65536 */

#define DST_Q4   ((OFF_FEAT + 2 * B * D) / 4)
#define DST_O24  (B * C / 4)
#define DST_QF4  (OFF_FEAT / 4)
#define DST_KF4  (OFF_FEAT / 4 + N_F4)
#define DST_P4   ((OFF_LBL + 2 * B) / 4)

// small-segment ranges (float4 indices)
#define SM_O2  (N_O4)                         /* after: output2 */
#define SM_Q   (2 * N_O4)                     /* after: q       */
#define SM_K   (2 * N_O4 + N_F4)              /* after: k       */
#define SM_P   (2 * N_O4 + 2 * N_F4)          /* after: pseudo  */
#define SM_TOT (2 * N_O4 + 2 * N_F4 + N_P4)   /* 209920 float4  */

// queue copy split: K1's slice sized to hide under roles (~25 µs at fat rate);
// K2 (lean) grid-strides the rest.
#define Q_TILES   (N_Q4 / 1024)               /* 8192 tiles of 1024 float4      */
#define K1_TILES  1664                        /* 26 MB payload ≈ roles duration */
#define POOL_BASE4 ((size_t)K1_TILES * 1024)  /* 1703936 */
#define POOL_N4    ((size_t)(Q_TILES - K1_TILES) * 1024)   /* 6684672 */

// K1 role boundaries: argmax | scoreprot | small | copy tiles
#define R1_SP     256                         /* [256,512): scoreprot           */
#define R1_SM     512                         /* [512,1332): small segments     */
#define SM_BLKS   ((SM_TOT + 255) / 256)      /* 820 */
#define R1_CP     (R1_SM + SM_BLKS)           /* 1332: copy tiles start         */
#define K1_GRID   (R1_CP + K1_TILES)          /* 2996 */

// K2: lean EMA + copy
#define R2_EMA    250                         /* 4 classes/block                */
#define K2_GRID   2048
#define TOT_THR2  ((size_t)K2_GRID * 256)     /* 524288 */

// ---------------- K1: argmax + scoreprot + small segments + copy slice ---------
// Shared memory hand-aliased; scoreprot path is the max: C+256+128=1384 floats.
__global__ __launch_bounds__(256) void k1_kernel(
    const float* __restrict__ q,
    const float* __restrict__ kk,
    const float* __restrict__ output,
    const float* __restrict__ output2,
    const float* __restrict__ partial_Y,
    const float* __restrict__ prototypes,
    const float4* __restrict__ queue,
    const float* __restrict__ queue_pseudo,
    int* __restrict__ labels,          // d_ws: [0,256) labels
    float* __restrict__ out)
{
    const int bid = blockIdx.x;
    const int tid = threadIdx.x;
    __shared__ float smem[1384];

    if (bid < B) {
        // ---- argmax of output*partial_Y per row (first-occurrence ties) -------
        float* sv = smem;                  // 256 floats
        int*   si = (int*)(smem + 256);    // 256 ints
        const float* row = output + (size_t)bid * C;
        const float* msk = partial_Y + (size_t)bid * C;

        float best = -INFINITY;
        int bidx = C;
        for (int c = tid; c < C; c += 256) {
            float v = row[c] * msk[c];
            if (v > best) { best = v; bidx = c; }
        }
        sv[tid] = best; si[tid] = bidx;
        __syncthreads();
        for (int s = 128; s > 0; s >>= 1) {
            if (tid < s) {
                float v2 = sv[tid + s]; int i2 = si[tid + s];
                if (v2 > sv[tid] || (v2 == sv[tid] && i2 < si[tid])) {
                    sv[tid] = v2; si[tid] = i2;
                }
            }
            __syncthreads();
        }
        if (tid == 0) {
            int lab = si[0];
            labels[bid] = lab;
            float f = (float)lab;
            out[OFF_LBL + bid]     = f;
            out[OFF_LBL + B + bid] = f;
        }
        return;
    }

    if (bid < R1_SM) {
        // ---- score_prot = softmax(q @ P^T), one row per block (orig protos) ---
        const int b = bid - R1_SP;
        float* logits = smem;              // C floats
        float* red    = smem + C;          // 256 floats
        float* qs     = smem + C + 256;    // 128 floats
        if (tid < D) qs[tid] = q[(size_t)b * D + tid];
        __syncthreads();

        for (int c = tid; c < C; c += 256) {
            const float4* p4 = (const float4*)(prototypes + (size_t)c * D);
            const float4* q4 = (const float4*)qs;
            float acc = 0.f;
            #pragma unroll
            for (int d = 0; d < D / 4; ++d) {
                float4 pv = p4[d];
                float4 qv = q4[d];
                acc += pv.x * qv.x + pv.y * qv.y + pv.z * qv.z + pv.w * qv.w;
            }
            logits[c] = acc;
        }
        __syncthreads();

        float lm = -INFINITY;
        for (int c = tid; c < C; c += 256) lm = fmaxf(lm, logits[c]);
        red[tid] = lm;
        __syncthreads();
        for (int s = 128; s > 0; s >>= 1) {
            if (tid < s) red[tid] = fmaxf(red[tid], red[tid + s]);
            __syncthreads();
        }
        const float m = red[0];
        __syncthreads();

        float psum = 0.f;
        for (int c = tid; c < C; c += 256) {
            float e = expf(logits[c] - m);
            logits[c] = e;
            psum += e;
        }
        red[tid] = psum;
        __syncthreads();
        for (int s = 128; s > 0; s >>= 1) {
            if (tid < s) red[tid] += red[tid + s];
            __syncthreads();
        }
        const float denom = red[0];

        for (int c = tid; c < C; c += 256)
            out[OFF_SCORE + (size_t)b * C + c] = logits[c] / denom;
        return;
    }

    if (bid < R1_CP) {
        // ---- small segments: output, output2, q->feat, k->feat, pseudo --------
        const size_t i = (size_t)(bid - R1_SM) * 256 + tid;
        float4* __restrict__ out4 = (float4*)out;
        if (i < SM_O2)       out4[i]                     = ((const float4*)output)[i];
        else if (i < SM_Q)   out4[DST_O24 + (i - SM_O2)] = ((const float4*)output2)[i - SM_O2];
        else if (i < SM_K)   out4[DST_QF4 + (i - SM_Q)]  = ((const float4*)q)[i - SM_Q];
        else if (i < SM_P)   out4[DST_KF4 + (i - SM_K)]  = ((const float4*)kk)[i - SM_K];
        else if (i < SM_TOT) out4[DST_P4 + (i - SM_P)]   = ((const float4*)queue_pseudo)[i - SM_P];
        return;
    }

    // ---- one-shot queue copy tile: keep HBM busy while roles run -------------
    const size_t base = (size_t)(bid - R1_CP) * 1024 + tid;
    float4* __restrict__ dst = (float4*)out + DST_Q4;
    float4 a = queue[base];
    float4 b = queue[base + 256];
    float4 c = queue[base + 512];
    float4 d = queue[base + 768];
    dst[base]       = a;
    dst[base + 256] = b;
    dst[base + 512] = c;
    dst[base + 768] = d;
}

// ---------------- K2: lean EMA + grid-stride copy (one kernel, no bubble) ------
// __launch_bounds__(256, 8): cap VGPR at 64 so copy waves can hit 32 waves/CU.
// LDS = 2 KB (EMA only). EMA blocks fall through to the copy after their role.
__global__ __launch_bounds__(256, 8) void k2_kernel(
    const float* __restrict__ q,
    const float* __restrict__ prototypes,
    const float4* __restrict__ queue,
    const int* __restrict__ labels,
    float* __restrict__ out)
{
    const int bid = blockIdx.x;
    const int tid = threadIdx.x;

    if (bid < R2_EMA) {
        // ---- EMA scatter + L2 normalize; 4 classes/block (2 at a time) --------
        __shared__ int   lab[B];
        __shared__ float ss[256];
        const int half = tid >> 7;
        const int d    = tid & 127;
        for (int i = tid; i < B; i += 256) lab[i] = labels[i];
        __syncthreads();

        #pragma unroll
        for (int kcl = 0; kcl < 2; ++kcl) {
            const int c = 4 * bid + 2 * kcl + half;
            float val = prototypes[(size_t)c * D + d];
            #pragma unroll 8
            for (int b = 0; b < B; ++b) {
                if (lab[b] == c) {
                    val = val * 0.99f + 0.01f * q[(size_t)b * D + d];
                }
            }
            ss[tid] = val * val;
            __syncthreads();
            for (int s = 64; s > 0; s >>= 1) {
                if (d < s) ss[tid] += ss[tid + s];
                __syncthreads();
            }
            float r = fmaxf(sqrtf(ss[half * 128]), 1e-12f);
            out[OFF_PROTO + (size_t)c * D + d] = val / r;
            __syncthreads();
        }
        // fall through to copy
    }

    // ---- grid-stride queue copy ----------------------------------------------
    const float4* __restrict__ srcq = queue + POOL_BASE4;
    float4* __restrict__ dstq = (float4*)out + DST_Q4 + POOL_BASE4;
    size_t i = (size_t)bid * 256 + tid;
    for (; i + 3 * TOT_THR2 < POOL_N4; i += 4 * TOT_THR2) {
        float4 a = srcq[i];
        float4 b = srcq[i +     TOT_THR2];
        float4 c = srcq[i + 2 * TOT_THR2];
        float4 d = srcq[i + 3 * TOT_THR2];
        dstq[i]                = a;
        dstq[i +     TOT_THR2] = b;
        dstq[i + 2 * TOT_THR2] = c;
        dstq[i + 3 * TOT_THR2] = d;
    }
    for (; i < POOL_N4; i += TOT_THR2)
        dstq[i] = srcq[i];
}

extern "C" void kernel_launch(void* const* d_in, const int* in_sizes, int n_in,
                              void* d_out, int out_size, void* d_ws, size_t ws_size,
                              hipStream_t stream) {
    const float* q            = (const float*)d_in[0];
    const float* k            = (const float*)d_in[1];
    const float* output       = (const float*)d_in[2];
    const float* output2      = (const float*)d_in[3];
    const float* partial_Y    = (const float*)d_in[4];
    const float* prototypes   = (const float*)d_in[5];
    const float* queue        = (const float*)d_in[6];
    const float* queue_pseudo = (const float*)d_in[7];

    float* out  = (float*)d_out;
    int* labels = (int*)d_ws;

    // K1: argmax + scoreprot + small segments, overlapped with a copy slice
    // sized to the roles' duration (1664 tiles ≈ 26 MB payload).
    k1_kernel<<<K1_GRID, 256, 0, stream>>>(
        q, k, output, output2, partial_Y, prototypes,
        (const float4*)queue, queue_pseudo, labels, out);

    // K2: lean EMA + remaining copy in ONE kernel (no serialization bubble;
    // EMA hides inside the copy; VGPR<=64, LDS 2KB for high copy occupancy).
    k2_kernel<<<K2_GRID, 256, 0, stream>>>(
        q, prototypes, (const float4*)queue, labels, out);
}